// Round 3
// baseline (358.270 us; speedup 1.0000x reference)
//
#include <hip/hip_runtime.h>

// MultiScaleSubsequenceExtractor: masked sliding-window means.
// B=128, L=1024, D=128, windows {4,8,16,32}; out rows/batch = 4040.
// R3: LDS-free register-sliding rewrite. Each wave = one 32-position strip of
// one batch; 64 lanes = 64 float2 channel columns. 4 running window sums slide
// in registers; lagged rows (i, i+4, i+8, i+16, i+32) are re-loaded from
// L1/L2 (recently touched) instead of an LDS round-trip. No barriers, no LDS,
// ~16 waves/CU. Window-count reciprocals precomputed into d_ws (2 MB) by a
// pre-kernel. Floor: 265 MB write + ~134 MB read ~= 63 us at 6.3 TB/s.

namespace {
constexpr int kB   = 128;
constexpr int kL   = 1024;
constexpr int kD   = 128;
constexpr int kD2  = kD / 2;          // 64 float2 per row
constexpr int ROUT = 4040;
constexpr int OFF4  = 0;
constexpr int OFF8  = 1021;
constexpr int OFF16 = 2038;
constexpr int OFF32 = 3047;
constexpr int P    = 32;              // positions per strip (one wave per strip)
constexpr int STRIPS = kB * (kL / P); // 4096 strips total
}

typedef float v2f __attribute__((ext_vector_type(2)));

__device__ __forceinline__ void nt_store2(v2f* p, v2f v) {
    __builtin_nontemporal_store(v, p);
}

// ---- pre-kernel: inv window counts per (b,i), packed float4 into d_ws ----
__global__ __launch_bounds__(256)
void inv_kernel(const int* __restrict__ mask, float4* __restrict__ invq) {
    const int idx = blockIdx.x * 256 + threadIdx.x;   // b*kL + i
    if (idx >= kB * kL) return;
    const int i = idx & (kL - 1);
    const int* mrow = mask + (idx - i);               // batch row start
    float c = 0.f, c4 = 0.f, c8 = 0.f, c16 = 0.f;
    #pragma unroll
    for (int j = 0; j < 32; ++j) {
        const int r = i + j;
        const float m = (r < kL) ? (float)mrow[r] : 0.f;
        c += m;
        if (j == 3)  c4  = c;
        if (j == 7)  c8  = c;
        if (j == 15) c16 = c;
    }
    invq[idx] = make_float4(1.f / fmaxf(c4, 1.f), 1.f / fmaxf(c8, 1.f),
                            1.f / fmaxf(c16, 1.f), 1.f / fmaxf(c, 1.f));
}

// ---- main kernel: register-sliding window sums, no LDS ----
__global__ __launch_bounds__(256)
void msse_kernel(const float* __restrict__ emb,
                 const int*   __restrict__ mask,
                 const float4* __restrict__ invq,
                 float*       __restrict__ out) {
    const int wave  = threadIdx.x >> 6;         // 0..3
    const int lane  = threadIdx.x & 63;         // float2 column
    const int strip = blockIdx.x * 4 + wave;    // [0, 4096)
    const int b     = strip >> 5;               // 32 strips per batch
    const int i0    = (strip & 31) * P;

    const v2f* __restrict__ e2 =
        reinterpret_cast<const v2f*>(emb) + (size_t)b * kL * kD2 + lane;
    const int* __restrict__ mrow = mask + b * kL;
    const float4* __restrict__ ivq = invq + b * kL;

    auto loadrow = [&](int r) -> v2f {
        v2f z; z.x = 0.f; z.y = 0.f;
        if (r < kL) {                        // wave-uniform guard
            v2f v = e2[(size_t)r * kD2];
            const float m = (float)mrow[r];
            z.x = v.x * m; z.y = v.y * m;
        }
        return z;
    };

    // init: sums over [i0, i0+w) for w in {4,8,16,32}
    v2f s4, s8, s16, s32;
    {
        v2f a; a.x = 0.f; a.y = 0.f;
        v2f t4 = a, t8 = a, t16 = a;
        #pragma unroll
        for (int j = 0; j < 32; ++j) {
            const v2f x = loadrow(i0 + j);   // i0+31 <= 1023 always
            a.x += x.x; a.y += x.y;
            if (j == 3)  t4  = a;
            if (j == 7)  t8  = a;
            if (j == 15) t16 = a;
        }
        s4 = t4; s8 = t8; s16 = t16; s32 = a;
    }

    v2f* ob = reinterpret_cast<v2f*>(out) + (size_t)b * ROUT * kD2 + lane;

    #pragma unroll 4
    for (int p = 0; p < P; ++p) {
        const int i = i0 + p;
        const float4 inv = ivq[i];           // same addr all lanes -> broadcast

        v2f o;
        if (i <= kL - 4)  { o.x = s4.x  * inv.x; o.y = s4.y  * inv.x;
                            nt_store2(ob + (size_t)(OFF4  + i) * kD2, o); }
        if (i <= kL - 8)  { o.x = s8.x  * inv.y; o.y = s8.y  * inv.y;
                            nt_store2(ob + (size_t)(OFF8  + i) * kD2, o); }
        if (i <= kL - 16) { o.x = s16.x * inv.z; o.y = s16.y * inv.z;
                            nt_store2(ob + (size_t)(OFF16 + i) * kD2, o); }
        if (i <= kL - 32) { o.x = s32.x * inv.w; o.y = s32.y * inv.w;
                            nt_store2(ob + (size_t)(OFF32 + i) * kD2, o); }

        // slide all windows to position i+1; lagged rows come from L1/L2
        const v2f x0 = loadrow(i);
        const v2f xa = loadrow(i + 4);
        const v2f xb = loadrow(i + 8);
        const v2f xc = loadrow(i + 16);
        const v2f xd = loadrow(i + 32);
        s4.x  += xa.x - x0.x;  s4.y  += xa.y - x0.y;
        s8.x  += xb.x - x0.x;  s8.y  += xb.y - x0.y;
        s16.x += xc.x - x0.x;  s16.y += xc.y - x0.y;
        s32.x += xd.x - x0.x;  s32.y += xd.y - x0.y;
    }
}

extern "C" void kernel_launch(void* const* d_in, const int* in_sizes, int n_in,
                              void* d_out, int out_size, void* d_ws, size_t ws_size,
                              hipStream_t stream) {
    const float* emb  = (const float*)d_in[0];
    const int*   mask = (const int*)d_in[1];
    float*       out  = (float*)d_out;
    float4*      invq = (float4*)d_ws;       // 128*1024*16 B = 2 MB

    inv_kernel<<<(kB * kL + 255) / 256, 256, 0, stream>>>(mask, invq);
    msse_kernel<<<STRIPS / 4, 256, 0, stream>>>(emb, mask, invq, out);
}